// Round 1
// baseline (212.544 us; speedup 1.0000x reference)
//
#include <hip/hip_runtime.h>
#include <hip/hip_bf16.h>

// HumanVAttention: QKV proj -> partial RoPE -> GQA block-sparse attn -> out proj
// B=1 S=4096 HID=2048 NH=16 NKV=4 HD=128 BLK=64 LOCAL=4 GNB=2 STRIDE=4 ROT=64

typedef short short8 __attribute__((ext_vector_type(8)));
typedef float f32x4 __attribute__((ext_vector_type(4)));

#define NEGV   (-1.0e9f)
#define SCALE  (0.08838834764831845f)

__device__ __forceinline__ void gload16(const void* g, void* l) {
  __builtin_amdgcn_global_load_lds(
      (const __attribute__((address_space(1))) unsigned int*)g,
      (__attribute__((address_space(3))) unsigned int*)l, 16, 0, 0);
}

// ---------------- elementwise convert hidden f32 -> bf16 ----------------
__global__ void conv_hidden(const float* __restrict__ H, __hip_bfloat16* __restrict__ X) {
  size_t t = (size_t)blockIdx.x * 256 + threadIdx.x;   // one float4 per thread
  float4 v = *(const float4*)(H + t * 4);
  __hip_bfloat16* o = X + t * 4;
  o[0] = __float2bfloat16(v.x); o[1] = __float2bfloat16(v.y);
  o[2] = __float2bfloat16(v.z); o[3] = __float2bfloat16(v.w);
}

// ---------------- tiled transpose f32[R][C] -> bf16 dst[C][R] ----------------
__global__ void transpose_f32_to_bf16(const float* __restrict__ src,
                                      __hip_bfloat16* __restrict__ dst,
                                      int R, int C) {
  __shared__ __hip_bfloat16 tile[64][73];
  int r0 = blockIdx.x * 64, c0 = blockIdx.y * 64;
  int c = threadIdx.x & 63, rq = threadIdx.x >> 6;
#pragma unroll
  for (int i = 0; i < 16; ++i) {
    int r = i * 4 + rq;
    tile[r][c] = __float2bfloat16(src[(size_t)(r0 + r) * C + c0 + c]);
  }
  __syncthreads();
#pragma unroll
  for (int i = 0; i < 16; ++i) {
    int cc = i * 4 + rq;
    dst[(size_t)(c0 + cc) * R + r0 + c] = tile[c][cc];
  }
}

// ---------------- V transpose: QKV[s][2560+c] (f32) -> Vt[c][s] (bf16) ----------------
__global__ void transpose_v(const float* __restrict__ QKV, __hip_bfloat16* __restrict__ Vt) {
  __shared__ __hip_bfloat16 tile[64][73];
  int s0 = blockIdx.x * 64, c0 = blockIdx.y * 64;
  int c = threadIdx.x & 63, rq = threadIdx.x >> 6;
#pragma unroll
  for (int i = 0; i < 16; ++i) {
    int r = i * 4 + rq;
    tile[r][c] = __float2bfloat16(QKV[(size_t)(s0 + r) * 3072 + 2560 + c0 + c]);
  }
  __syncthreads();
#pragma unroll
  for (int i = 0; i < 16; ++i) {
    int cc = i * 4 + rq;
    Vt[(size_t)(c0 + cc) * 4096 + s0 + c] = tile[c][cc];
  }
}

// ---------------- RoPE on q,k (first 64 dims of each 128-d head), f32 -> bf16 ----------------
__global__ void rope_qk(const float* __restrict__ QKV, const float* __restrict__ cosb,
                        const float* __restrict__ sinb, __hip_bfloat16* __restrict__ Qb,
                        __hip_bfloat16* __restrict__ Kb) {
  size_t t = (size_t)blockIdx.x * 256 + threadIdx.x;  // one 4-elem group
  const size_t QT = (size_t)4096 * 512;               // q groups: 2048/4 per row
  int s, cg; const float* row; __hip_bfloat16* dst;
  if (t < QT) {
    s = (int)(t >> 9); cg = (int)(t & 511) * 4;
    row = QKV + (size_t)s * 3072;
    dst = Qb + (size_t)s * 2048 + cg;
  } else {
    size_t tk = t - QT;
    s = (int)(tk >> 7); cg = (int)(tk & 127) * 4;
    row = QKV + (size_t)s * 3072 + 2048;
    dst = Kb + (size_t)s * 512 + cg;
  }
  int d = cg & 127;
  float4 v = *(const float4*)(row + cg);
  float o0, o1, o2, o3;
  if (d < 64) {
    float4 cs = *(const float4*)(cosb + (size_t)s * 64 + d);
    float4 sn = *(const float4*)(sinb + (size_t)s * 64 + d);
    float4 p  = *(const float4*)(row + cg + (d < 32 ? 32 : -32));
    float sg = (d < 32) ? -1.f : 1.f;
    o0 = v.x * cs.x + sg * p.x * sn.x;
    o1 = v.y * cs.y + sg * p.y * sn.y;
    o2 = v.z * cs.z + sg * p.z * sn.z;
    o3 = v.w * cs.w + sg * p.w * sn.w;
  } else { o0 = v.x; o1 = v.y; o2 = v.z; o3 = v.w; }
  dst[0] = __float2bfloat16(o0); dst[1] = __float2bfloat16(o1);
  dst[2] = __float2bfloat16(o2); dst[3] = __float2bfloat16(o3);
}

// ---------------- GEMM: C[M][N] f32 = A[M][K] bf16 . Bt[N][K]^T bf16 ----------------
// 128x128 tile, BK=32, 256 threads (2x2 waves of 64x64), 16x16x32 MFMA (m97 structure)
__global__ __launch_bounds__(256) void gemm_bt(
    const __hip_bfloat16* __restrict__ A, const __hip_bfloat16* __restrict__ Bt,
    float* __restrict__ C, int M, int N, int K) {
  const int tid = threadIdx.x;
  const int wave = tid >> 6, lane = tid & 63;
  const int l15 = lane & 15, lg = lane >> 4;
  const int bm = blockIdx.x, bn = blockIdx.y;
  const int wm = wave >> 1, wn = wave & 1;

  __shared__ __hip_bfloat16 As[128 * 32];
  __shared__ __hip_bfloat16 Bs[128 * 32];

  f32x4 acc[4][4] = {};
  const int srow = lane >> 2;          // staging row within 16-row segment
  const int scol = (lane & 3) * 8;     // staging col (elements)
  const size_t abase = (size_t)bm * 128 * K;
  const size_t bbase = (size_t)bn * 128 * K;

  for (int k0 = 0; k0 < K; k0 += 32) {
#pragma unroll
    for (int i = 0; i < 2; ++i) {
      int seg = i * 4 + wave;          // 0..7, 16 rows each
      int row = seg * 16 + srow;
      gload16(A + abase + (size_t)row * K + k0 + scol, &As[seg * 512]);
      gload16(Bt + bbase + (size_t)row * K + k0 + scol, &Bs[seg * 512]);
    }
    __syncthreads();
    short8 af[4], bf[4];
#pragma unroll
    for (int mi = 0; mi < 4; ++mi)
      af[mi] = *(const short8*)&As[(wm * 64 + mi * 16 + l15) * 32 + lg * 8];
#pragma unroll
    for (int ni = 0; ni < 4; ++ni)
      bf[ni] = *(const short8*)&Bs[(wn * 64 + ni * 16 + l15) * 32 + lg * 8];
#pragma unroll
    for (int mi = 0; mi < 4; ++mi)
#pragma unroll
      for (int ni = 0; ni < 4; ++ni)
        acc[mi][ni] = __builtin_amdgcn_mfma_f32_16x16x32_bf16(af[mi], bf[ni], acc[mi][ni], 0, 0, 0);
    __syncthreads();
  }
#pragma unroll
  for (int mi = 0; mi < 4; ++mi)
#pragma unroll
    for (int ni = 0; ni < 4; ++ni) {
      int row = bm * 128 + wm * 64 + mi * 16 + lg * 4;
      int col = bn * 128 + wn * 64 + ni * 16 + l15;
#pragma unroll
      for (int r = 0; r < 4; ++r)
        C[(size_t)(row + r) * N + col] = acc[mi][ni][r];
    }
}

// ---------------- block-sparse attention ----------------
// grid = nb*NH = 1024 blocks; block = 256 threads = 4 waves; wave w owns q-rows [w*16, w*16+16)
__global__ __launch_bounds__(256, 2) void attn_kernel(
    const __hip_bfloat16* __restrict__ Qb,  // [4096][2048]
    const __hip_bfloat16* __restrict__ Kb,  // [4096][512]
    const __hip_bfloat16* __restrict__ Vt,  // [512][4096]  (channel-major)
    const float* __restrict__ amask,        // [4096]
    __hip_bfloat16* __restrict__ AO)        // [4096][2048]
{
  const int bid = blockIdx.x;
  const int h = bid & 15;
  const int bi = bid >> 4;
  const int kvh = h >> 2;
  const int tid = threadIdx.x;
  const int wave = tid >> 6, lane = tid & 63;
  const int l15 = lane & 15, lg = lane >> 4;

  // static block selection (matches _select_key_blocks): <=6 blocks
  int sel[6]; int nsel = 0;
  {
    int gtop = bi >> 2;  // index of last stride-4 multiple <= bi
    for (int j = 0; j <= bi; ++j) {
      bool pick = (j == 0) || (j >= bi - 3) || (((j & 3) == 0) && ((j >> 2) >= gtop - 1));
      if (pick && nsel < 6) sel[nsel++] = j;
    }
  }

  __shared__ __hip_bfloat16 kvs[128 * 72];   // K phase: [64][136]; V phase: [128][72]
  __shared__ __hip_bfloat16 Pb[64 * 72];     // P tile [64 q][64 k + pad]

  // Q fragments in registers (A operand, 4 k-steps of 32)
  short8 qf[4];
  {
    const __hip_bfloat16* qbase =
        Qb + (size_t)(bi * 64 + wave * 16 + l15) * 2048 + h * 128 + lg * 8;
#pragma unroll
    for (int ks = 0; ks < 4; ++ks) qf[ks] = *(const short8*)(qbase + ks * 32);
  }

  // ---- phase 1: scores for all selected blocks (held in registers) ----
  f32x4 sc[6][4] = {};
#pragma unroll
  for (int j = 0; j < 6; ++j) {
    if (j < nsel) {
      int kb = sel[j];
#pragma unroll
      for (int i = 0; i < 4; ++i) {
        int e = (i * 256 + tid) * 8;        // 64*128 elements
        int r = e >> 7, c = e & 127;
        short8 v = *(const short8*)(Kb + (size_t)(kb * 64 + r) * 512 + kvh * 128 + c);
        *(short8*)&kvs[r * 136 + c] = v;
      }
      __syncthreads();
#pragma unroll
      for (int nf = 0; nf < 4; ++nf)
#pragma unroll
        for (int ks = 0; ks < 4; ++ks) {
          short8 bfr = *(const short8*)&kvs[(nf * 16 + l15) * 136 + ks * 32 + lg * 8];
          sc[j][nf] = __builtin_amdgcn_mfma_f32_16x16x32_bf16(qf[ks], bfr, sc[j][nf], 0, 0, 0);
        }
      __syncthreads();
    }
  }

  // ---- phase 2: mask + softmax (rows live in (lg, r)) ----
  float rowmax[4] = {-3.0e38f, -3.0e38f, -3.0e38f, -3.0e38f};
#pragma unroll
  for (int j = 0; j < 6; ++j) {
    if (j >= nsel) continue;
    int kb = sel[j];
#pragma unroll
    for (int nf = 0; nf < 4; ++nf) {
      int keyg = kb * 64 + nf * 16 + l15;
      float mterm = (1.0f - amask[keyg]) * NEGV;
      int keyl = nf * 16 + l15;
#pragma unroll
      for (int r = 0; r < 4; ++r) {
        float s = sc[j][nf][r] * SCALE + mterm;
        if (kb == bi) {
          int qrow = wave * 16 + lg * 4 + r;   // wait: local row within block is lg*4+r + wave*16
          if (keyl > (qrow & 63)) s = NEGV;
        }
        sc[j][nf][r] = s;
        rowmax[r] = fmaxf(rowmax[r], s);
      }
    }
  }
#pragma unroll
  for (int r = 0; r < 4; ++r) {
    float v = rowmax[r];
    v = fmaxf(v, __shfl_xor(v, 1)); v = fmaxf(v, __shfl_xor(v, 2));
    v = fmaxf(v, __shfl_xor(v, 4)); v = fmaxf(v, __shfl_xor(v, 8));
    rowmax[r] = v;
  }
  float rinv[4] = {0.f, 0.f, 0.f, 0.f};
#pragma unroll
  for (int j = 0; j < 6; ++j) {
    if (j >= nsel) continue;
#pragma unroll
    for (int nf = 0; nf < 4; ++nf)
#pragma unroll
      for (int r = 0; r < 4; ++r) {
        float p = __expf(sc[j][nf][r] - rowmax[r]);
        sc[j][nf][r] = p;
        rinv[r] += p;
      }
  }
#pragma unroll
  for (int r = 0; r < 4; ++r) {
    float v = rinv[r];
    v += __shfl_xor(v, 1); v += __shfl_xor(v, 2);
    v += __shfl_xor(v, 4); v += __shfl_xor(v, 8);
    rinv[r] = 1.0f / v;
  }

  // ---- phase 3: PV ----
  f32x4 oacc[8] = {};
#pragma unroll
  for (int j = 0; j < 6; ++j) {
    if (j < nsel) {
      int kb = sel[j];
      // write normalized P tile (each wave its own 16 rows)
#pragma unroll
      for (int nf = 0; nf < 4; ++nf)
#pragma unroll
        for (int r = 0; r < 4; ++r) {
          int qrow = wave * 16 + lg * 4 + r;
          Pb[qrow * 72 + nf * 16 + l15] = __float2bfloat16(sc[j][nf][r] * rinv[r]);
        }
      // stage V block: Vt[kvh*128+d][4096] -> kvs[d][72]
#pragma unroll
      for (int i = 0; i < 4; ++i) {
        int e = (i * 256 + tid) * 8;        // 128*64 elements
        int d = e >> 6, c = e & 63;
        short8 v = *(const short8*)(Vt + (size_t)(kvh * 128 + d) * 4096 + kb * 64 + c);
        *(short8*)&kvs[d * 72 + c] = v;
      }
      __syncthreads();
#pragma unroll
      for (int ks = 0; ks < 2; ++ks) {
        short8 pa = *(const short8*)&Pb[(wave * 16 + l15) * 72 + ks * 32 + lg * 8];
#pragma unroll
        for (int df = 0; df < 8; ++df) {
          short8 vb = *(const short8*)&kvs[(df * 16 + l15) * 72 + ks * 32 + lg * 8];
          oacc[df] = __builtin_amdgcn_mfma_f32_16x16x32_bf16(pa, vb, oacc[df], 0, 0, 0);
        }
      }
      __syncthreads();
    }
  }

  // ---- phase 4: write AO ----
#pragma unroll
  for (int df = 0; df < 8; ++df)
#pragma unroll
    for (int r = 0; r < 4; ++r) {
      int qrow = bi * 64 + wave * 16 + lg * 4 + r;
      AO[(size_t)qrow * 2048 + h * 128 + df * 16 + l15] = __float2bfloat16(oacc[df][r]);
    }
}

// ---------------- launch ----------------
extern "C" void kernel_launch(void* const* d_in, const int* in_sizes, int n_in,
                              void* d_out, int out_size, void* d_ws, size_t ws_size,
                              hipStream_t stream) {
  const float* hidden = (const float*)d_in[0];
  const float* cosb   = (const float*)d_in[1];
  const float* sinb   = (const float*)d_in[2];
  const float* Wq     = (const float*)d_in[3];
  const float* Wk     = (const float*)d_in[4];
  const float* Wv     = (const float*)d_in[5];
  const float* Wo     = (const float*)d_in[6];
  const float* amask  = (const float*)d_in[7];

  char* ws = (char*)d_ws;
  __hip_bfloat16* Xb  = (__hip_bfloat16*)(ws);                // 16,777,216 B  [4096][2048]
  __hip_bfloat16* Wt  = (__hip_bfloat16*)(ws + 16777216);     // 12,582,912 B  [3072][2048]
  __hip_bfloat16* Wot = (__hip_bfloat16*)(ws + 29360128);     //  8,388,608 B  [2048][2048]
  float*          QKV = (float*)(ws + 37748736);              // 50,331,648 B  [4096][3072]
  __hip_bfloat16* Qb  = (__hip_bfloat16*)(ws + 88080384);     // 16,777,216 B  [4096][2048]
  __hip_bfloat16* Kb  = (__hip_bfloat16*)(ws + 104857600);    //  4,194,304 B  [4096][512]
  __hip_bfloat16* Vt  = (__hip_bfloat16*)(ws + 109051904);    //  4,194,304 B  [512][4096]
  __hip_bfloat16* AO  = Xb;  // Xb dead after GEMM1; reuse for attention output

  conv_hidden<<<8192, 256, 0, stream>>>(hidden, Xb);
  transpose_f32_to_bf16<<<dim3(32, 32), 256, 0, stream>>>(Wq, Wt, 2048, 2048);
  transpose_f32_to_bf16<<<dim3(32, 8),  256, 0, stream>>>(Wk, Wt + (size_t)2048 * 2048, 2048, 512);
  transpose_f32_to_bf16<<<dim3(32, 8),  256, 0, stream>>>(Wv, Wt + (size_t)2560 * 2048, 2048, 512);
  transpose_f32_to_bf16<<<dim3(32, 32), 256, 0, stream>>>(Wo, Wot, 2048, 2048);

  gemm_bt<<<dim3(32, 24), 256, 0, stream>>>(Xb, Wt, QKV, 4096, 3072, 2048);

  rope_qk<<<10240, 256, 0, stream>>>(QKV, cosb, sinb, Qb, Kb);
  transpose_v<<<dim3(64, 8), 256, 0, stream>>>(QKV, Vt);

  attn_kernel<<<1024, 256, 0, stream>>>(Qb, Kb, Vt, amask, AO);

  gemm_bt<<<dim3(32, 16), 256, 0, stream>>>(AO, Wot, (float*)d_out, 4096, 2048, 2048);
}

// Round 3
// 182.005 us; speedup vs baseline: 1.1678x; 1.1678x over previous
//
#include <hip/hip_runtime.h>
#include <hip/hip_bf16.h>

// HumanVAttention: QKV proj -> partial RoPE -> GQA block-sparse attn -> out proj
// B=1 S=4096 HID=2048 NH=16 NKV=4 HD=128 BLK=64 LOCAL=4 GNB=2 STRIDE=4 ROT=64

typedef short short8 __attribute__((ext_vector_type(8)));
typedef float f32x4 __attribute__((ext_vector_type(4)));

#define NEGV   (-1.0e9f)
#define SCALE  (0.08838834764831845f)

__device__ __forceinline__ void gload16(const void* g, void* l) {
  __builtin_amdgcn_global_load_lds(
      (const __attribute__((address_space(1))) unsigned int*)g,
      (__attribute__((address_space(3))) unsigned int*)l, 16, 0, 0);
}

__device__ __forceinline__ float bf2f(short s) {
  union { unsigned u; float f; } c;
  c.u = ((unsigned)(unsigned short)s) << 16;
  return c.f;
}

__device__ __forceinline__ short f2bf_s(float f) {
  __hip_bfloat16 b = __float2bfloat16(f);
  short s;
  __builtin_memcpy(&s, &b, 2);
  return s;
}

// ---------------- elementwise convert hidden f32 -> bf16 ----------------
__global__ void conv_hidden(const float* __restrict__ H, __hip_bfloat16* __restrict__ X) {
  size_t t = (size_t)blockIdx.x * 256 + threadIdx.x;   // one float4 per thread
  float4 v = *(const float4*)(H + t * 4);
  __hip_bfloat16* o = X + t * 4;
  o[0] = __float2bfloat16(v.x); o[1] = __float2bfloat16(v.y);
  o[2] = __float2bfloat16(v.z); o[3] = __float2bfloat16(v.w);
}

// ---------------- tiled transpose f32[R][C] -> bf16 dst[C][R] ----------------
__global__ void transpose_f32_to_bf16(const float* __restrict__ src,
                                      __hip_bfloat16* __restrict__ dst,
                                      int R, int C) {
  __shared__ __hip_bfloat16 tile[64][73];
  int r0 = blockIdx.x * 64, c0 = blockIdx.y * 64;
  int c = threadIdx.x & 63, rq = threadIdx.x >> 6;
#pragma unroll
  for (int i = 0; i < 16; ++i) {
    int r = i * 4 + rq;
    tile[r][c] = __float2bfloat16(src[(size_t)(r0 + r) * C + c0 + c]);
  }
  __syncthreads();
#pragma unroll
  for (int i = 0; i < 16; ++i) {
    int cc = i * 4 + rq;
    dst[(size_t)(c0 + cc) * R + r0 + c] = tile[c][cc];
  }
}

// ---------------- V transpose: QKVb[s][2560+c] (bf16) -> Vt[c][s] (bf16) ----------------
__global__ void transpose_v(const __hip_bfloat16* __restrict__ QKV,
                            __hip_bfloat16* __restrict__ Vt) {
  __shared__ __hip_bfloat16 tile[64][73];
  int s0 = blockIdx.x * 64, c0 = blockIdx.y * 64;
  int c = threadIdx.x & 63, rq = threadIdx.x >> 6;
#pragma unroll
  for (int i = 0; i < 16; ++i) {
    int r = i * 4 + rq;
    tile[r][c] = QKV[(size_t)(s0 + r) * 3072 + 2560 + c0 + c];
  }
  __syncthreads();
#pragma unroll
  for (int i = 0; i < 16; ++i) {
    int cc = i * 4 + rq;
    Vt[(size_t)(c0 + cc) * 4096 + s0 + c] = tile[c][cc];
  }
}

// ---------------- RoPE on q,k (first 64 dims of each 128-d head), bf16 -> bf16 ----------------
__global__ void rope_qk(const __hip_bfloat16* __restrict__ QKV, const float* __restrict__ cosb,
                        const float* __restrict__ sinb, __hip_bfloat16* __restrict__ Qb,
                        __hip_bfloat16* __restrict__ Kb) {
  size_t t = (size_t)blockIdx.x * 256 + threadIdx.x;  // one 8-elem group
  const size_t QT = (size_t)4096 * 256;               // q groups: 2048/8 per row
  int s, cg; const __hip_bfloat16* row; __hip_bfloat16* dst;
  if (t < QT) {
    s = (int)(t >> 8); cg = (int)(t & 255) * 8;
    row = QKV + (size_t)s * 3072;
    dst = Qb + (size_t)s * 2048 + cg;
  } else {
    size_t tk = t - QT;
    s = (int)(tk >> 6); cg = (int)(tk & 63) * 8;
    row = QKV + (size_t)s * 3072 + 2048;
    dst = Kb + (size_t)s * 512 + cg;
  }
  int d = cg & 127;
  short8 v = *(const short8*)(row + cg);
  if (d < 64) {
    short8 p = *(const short8*)(row + cg + (d < 32 ? 32 : -32));
    float sg = (d < 32) ? -1.f : 1.f;
    const float* cp = cosb + (size_t)s * 64 + d;
    const float* sp = sinb + (size_t)s * 64 + d;
    float4 c0 = *(const float4*)cp, c1 = *(const float4*)(cp + 4);
    float4 s0 = *(const float4*)sp, s1 = *(const float4*)(sp + 4);
    float cs[8] = {c0.x, c0.y, c0.z, c0.w, c1.x, c1.y, c1.z, c1.w};
    float sn[8] = {s0.x, s0.y, s0.z, s0.w, s1.x, s1.y, s1.z, s1.w};
    short8 o;
#pragma unroll
    for (int i = 0; i < 8; ++i) {
      float r = bf2f(v[i]) * cs[i] + sg * bf2f(p[i]) * sn[i];
      o[i] = f2bf_s(r);
    }
    *(short8*)dst = o;
  } else {
    *(short8*)dst = v;
  }
}

// ---------------- GEMM: C[M][N] = A[M][K] bf16 . Bt[N][K]^T bf16 ----------------
// 128x128 tile, BK=64, 256 threads (2x2 waves of 64x64), 16x16x32 MFMA.
// LDS layout [128 rows][64 cols], staged linearly by global_load_lds; bank-conflict
// swizzle done by pre-swizzling the GLOBAL source column (slot ^= row&7, 16B slots)
// and applying the same XOR on the ds_read side (rule #21: both-sides involution).
template <typename OutT>
__global__ __launch_bounds__(256) void gemm_bt(
    const __hip_bfloat16* __restrict__ A, const __hip_bfloat16* __restrict__ Bt,
    OutT* __restrict__ C, int M, int N, int K) {
  const int tid = threadIdx.x;
  const int wave = tid >> 6, lane = tid & 63;
  const int l15 = lane & 15, lg = lane >> 4;
  const int bm = blockIdx.x, bn = blockIdx.y;
  const int wm = wave >> 1, wn = wave & 1;

  __shared__ __hip_bfloat16 As[128 * 64];
  __shared__ __hip_bfloat16 Bs[128 * 64];

  f32x4 acc[4][4] = {};
  const int lrow = lane >> 3;               // 0..7: row within 8-row segment
  const int lslot = lane & 7;               // 16B slot within 128B row
  const int scol = (lslot ^ lrow) * 8;      // pre-swizzled global col (elements)
  const size_t abase = (size_t)bm * 128 * K;
  const size_t bbase = (size_t)bn * 128 * K;
  const int r3 = l15 & 7;                   // fragment rows: (..*16 + l15)&7 == l15&7

  for (int k0 = 0; k0 < K; k0 += 64) {
#pragma unroll
    for (int i = 0; i < 4; ++i) {
      int seg = i * 4 + wave;               // 0..15, 8 rows each
      int row = seg * 8 + lrow;
      gload16(A + abase + (size_t)row * K + k0 + scol, &As[seg * 512]);
      gload16(Bt + bbase + (size_t)row * K + k0 + scol, &Bs[seg * 512]);
    }
    __syncthreads();
#pragma unroll
    for (int ks = 0; ks < 2; ++ks) {
      const int slot = (ks * 4 + lg) ^ r3;  // swizzled 16B slot for ds_read
      short8 af[4], bf[4];
#pragma unroll
      for (int mi = 0; mi < 4; ++mi)
        af[mi] = *(const short8*)&As[(wm * 64 + mi * 16 + l15) * 64 + slot * 8];
#pragma unroll
      for (int ni = 0; ni < 4; ++ni)
        bf[ni] = *(const short8*)&Bs[(wn * 64 + ni * 16 + l15) * 64 + slot * 8];
#pragma unroll
      for (int mi = 0; mi < 4; ++mi)
#pragma unroll
        for (int ni = 0; ni < 4; ++ni)
          acc[mi][ni] = __builtin_amdgcn_mfma_f32_16x16x32_bf16(af[mi], bf[ni], acc[mi][ni], 0, 0, 0);
    }
    __syncthreads();
  }
#pragma unroll
  for (int mi = 0; mi < 4; ++mi)
#pragma unroll
    for (int ni = 0; ni < 4; ++ni) {
      int row = bm * 128 + wm * 64 + mi * 16 + lg * 4;
      int col = bn * 128 + wn * 64 + ni * 16 + l15;
#pragma unroll
      for (int r = 0; r < 4; ++r) {
        float v = acc[mi][ni][r];
        if constexpr (__hip_internal::is_same<OutT, float>::value)
          C[(size_t)(row + r) * N + col] = v;
        else
          C[(size_t)(row + r) * N + col] = __float2bfloat16(v);
      }
    }
}

// ---------------- block-sparse attention ----------------
// grid = nb*NH = 1024 blocks; block = 256 threads = 4 waves; wave w owns q-rows [w*16, w*16+16)
__global__ __launch_bounds__(256, 2) void attn_kernel(
    const __hip_bfloat16* __restrict__ Qb,  // [4096][2048]
    const __hip_bfloat16* __restrict__ Kb,  // [4096][512]
    const __hip_bfloat16* __restrict__ Vt,  // [512][4096]  (channel-major)
    const float* __restrict__ amask,        // [4096]
    __hip_bfloat16* __restrict__ AO)        // [4096][2048]
{
  const int bid = blockIdx.x;
  const int h = bid & 15;
  const int bi = bid >> 4;
  const int kvh = h >> 2;
  const int tid = threadIdx.x;
  const int wave = tid >> 6, lane = tid & 63;
  const int l15 = lane & 15, lg = lane >> 4;

  // static block selection (matches _select_key_blocks): <=6 blocks
  int sel[6]; int nsel = 0;
  {
    int gtop = bi >> 2;  // index of last stride-4 multiple <= bi
    for (int j = 0; j <= bi; ++j) {
      bool pick = (j == 0) || (j >= bi - 3) || (((j & 3) == 0) && ((j >> 2) >= gtop - 1));
      if (pick && nsel < 6) sel[nsel++] = j;
    }
  }

  __shared__ __hip_bfloat16 kvs[128 * 72];   // K phase: [64][136]; V phase: [128][72]
  __shared__ __hip_bfloat16 Pb[64 * 72];     // P tile [64 q][64 k + pad]

  // Q fragments in registers (A operand, 4 k-steps of 32)
  short8 qf[4];
  {
    const __hip_bfloat16* qbase =
        Qb + (size_t)(bi * 64 + wave * 16 + l15) * 2048 + h * 128 + lg * 8;
#pragma unroll
    for (int ks = 0; ks < 4; ++ks) qf[ks] = *(const short8*)(qbase + ks * 32);
  }

  // ---- phase 1: scores for all selected blocks (held in registers) ----
  f32x4 sc[6][4] = {};
#pragma unroll
  for (int j = 0; j < 6; ++j) {
    if (j < nsel) {
      int kb = sel[j];
#pragma unroll
      for (int i = 0; i < 4; ++i) {
        int e = (i * 256 + tid) * 8;        // 64*128 elements
        int r = e >> 7, c = e & 127;
        short8 v = *(const short8*)(Kb + (size_t)(kb * 64 + r) * 512 + kvh * 128 + c);
        *(short8*)&kvs[r * 136 + c] = v;
      }
      __syncthreads();
#pragma unroll
      for (int nf = 0; nf < 4; ++nf)
#pragma unroll
        for (int ks = 0; ks < 4; ++ks) {
          short8 bfr = *(const short8*)&kvs[(nf * 16 + l15) * 136 + ks * 32 + lg * 8];
          sc[j][nf] = __builtin_amdgcn_mfma_f32_16x16x32_bf16(qf[ks], bfr, sc[j][nf], 0, 0, 0);
        }
      __syncthreads();
    }
  }

  // ---- phase 2: mask + softmax (rows live in (lg, r)) ----
  float rowmax[4] = {-3.0e38f, -3.0e38f, -3.0e38f, -3.0e38f};
#pragma unroll
  for (int j = 0; j < 6; ++j) {
    if (j >= nsel) continue;
    int kb = sel[j];
#pragma unroll
    for (int nf = 0; nf < 4; ++nf) {
      int keyg = kb * 64 + nf * 16 + l15;
      float mterm = (1.0f - amask[keyg]) * NEGV;
      int keyl = nf * 16 + l15;
#pragma unroll
      for (int r = 0; r < 4; ++r) {
        float s = sc[j][nf][r] * SCALE + mterm;
        if (kb == bi) {
          int qrow = wave * 16 + lg * 4 + r;
          if (keyl > qrow) s = NEGV;
        }
        sc[j][nf][r] = s;
        rowmax[r] = fmaxf(rowmax[r], s);
      }
    }
  }
#pragma unroll
  for (int r = 0; r < 4; ++r) {
    float v = rowmax[r];
    v = fmaxf(v, __shfl_xor(v, 1)); v = fmaxf(v, __shfl_xor(v, 2));
    v = fmaxf(v, __shfl_xor(v, 4)); v = fmaxf(v, __shfl_xor(v, 8));
    rowmax[r] = v;
  }
  float rinv[4] = {0.f, 0.f, 0.f, 0.f};
#pragma unroll
  for (int j = 0; j < 6; ++j) {
    if (j >= nsel) continue;
#pragma unroll
    for (int nf = 0; nf < 4; ++nf)
#pragma unroll
      for (int r = 0; r < 4; ++r) {
        float p = __expf(sc[j][nf][r] - rowmax[r]);
        sc[j][nf][r] = p;
        rinv[r] += p;
      }
  }
#pragma unroll
  for (int r = 0; r < 4; ++r) {
    float v = rinv[r];
    v += __shfl_xor(v, 1); v += __shfl_xor(v, 2);
    v += __shfl_xor(v, 4); v += __shfl_xor(v, 8);
    rinv[r] = 1.0f / v;
  }

  // ---- phase 3: PV ----
  f32x4 oacc[8] = {};
#pragma unroll
  for (int j = 0; j < 6; ++j) {
    if (j < nsel) {
      int kb = sel[j];
      // write normalized P tile (each wave its own 16 rows)
#pragma unroll
      for (int nf = 0; nf < 4; ++nf)
#pragma unroll
        for (int r = 0; r < 4; ++r) {
          int qrow = wave * 16 + lg * 4 + r;
          Pb[qrow * 72 + nf * 16 + l15] = __float2bfloat16(sc[j][nf][r] * rinv[r]);
        }
      // stage V block: Vt[kvh*128+d][4096] -> kvs[d][72]
#pragma unroll
      for (int i = 0; i < 4; ++i) {
        int e = (i * 256 + tid) * 8;        // 128*64 elements
        int d = e >> 6, c = e & 63;
        short8 v = *(const short8*)(Vt + (size_t)(kvh * 128 + d) * 4096 + kb * 64 + c);
        *(short8*)&kvs[d * 72 + c] = v;
      }
      __syncthreads();
#pragma unroll
      for (int ks = 0; ks < 2; ++ks) {
        short8 pa = *(const short8*)&Pb[(wave * 16 + l15) * 72 + ks * 32 + lg * 8];
#pragma unroll
        for (int df = 0; df < 8; ++df) {
          short8 vb = *(const short8*)&kvs[(df * 16 + l15) * 72 + ks * 32 + lg * 8];
          oacc[df] = __builtin_amdgcn_mfma_f32_16x16x32_bf16(pa, vb, oacc[df], 0, 0, 0);
        }
      }
      __syncthreads();
    }
  }

  // ---- phase 4: write AO ----
#pragma unroll
  for (int df = 0; df < 8; ++df)
#pragma unroll
    for (int r = 0; r < 4; ++r) {
      int qrow = bi * 64 + wave * 16 + lg * 4 + r;
      AO[(size_t)qrow * 2048 + h * 128 + df * 16 + l15] = __float2bfloat16(oacc[df][r]);
    }
}

// ---------------- launch ----------------
extern "C" void kernel_launch(void* const* d_in, const int* in_sizes, int n_in,
                              void* d_out, int out_size, void* d_ws, size_t ws_size,
                              hipStream_t stream) {
  const float* hidden = (const float*)d_in[0];
  const float* cosb   = (const float*)d_in[1];
  const float* sinb   = (const float*)d_in[2];
  const float* Wq     = (const float*)d_in[3];
  const float* Wk     = (const float*)d_in[4];
  const float* Wv     = (const float*)d_in[5];
  const float* Wo     = (const float*)d_in[6];
  const float* amask  = (const float*)d_in[7];

  char* ws = (char*)d_ws;
  __hip_bfloat16* Xb   = (__hip_bfloat16*)(ws);               // 16,777,216 B  [4096][2048]
  __hip_bfloat16* Wt   = (__hip_bfloat16*)(ws + 16777216);    // 12,582,912 B  [3072][2048]
  __hip_bfloat16* Wot  = (__hip_bfloat16*)(ws + 29360128);    //  8,388,608 B  [2048][2048]
  __hip_bfloat16* QKVb = (__hip_bfloat16*)(ws + 37748736);    // 25,165,824 B  [4096][3072]
  __hip_bfloat16* Qb   = (__hip_bfloat16*)(ws + 62914560);    // 16,777,216 B  [4096][2048]
  __hip_bfloat16* Kb   = (__hip_bfloat16*)(ws + 79691776);    //  4,194,304 B  [4096][512]
  __hip_bfloat16* Vt   = (__hip_bfloat16*)(ws + 83886080);    //  4,194,304 B  [512][4096]
  __hip_bfloat16* AO   = Xb;  // Xb dead after GEMM1; reuse for attention output

  conv_hidden<<<8192, 256, 0, stream>>>(hidden, Xb);
  transpose_f32_to_bf16<<<dim3(32, 32), 256, 0, stream>>>(Wq, Wt, 2048, 2048);
  transpose_f32_to_bf16<<<dim3(32, 8),  256, 0, stream>>>(Wk, Wt + (size_t)2048 * 2048, 2048, 512);
  transpose_f32_to_bf16<<<dim3(32, 8),  256, 0, stream>>>(Wv, Wt + (size_t)2560 * 2048, 2048, 512);
  transpose_f32_to_bf16<<<dim3(32, 32), 256, 0, stream>>>(Wo, Wot, 2048, 2048);

  gemm_bt<__hip_bfloat16><<<dim3(32, 24), 256, 0, stream>>>(Xb, Wt, QKVb, 4096, 3072, 2048);

  rope_qk<<<5120, 256, 0, stream>>>(QKVb, cosb, sinb, Qb, Kb);
  transpose_v<<<dim3(64, 8), 256, 0, stream>>>(QKVb, Vt);

  attn_kernel<<<1024, 256, 0, stream>>>(Qb, Kb, Vt, amask, AO);

  gemm_bt<float><<<dim3(32, 16), 256, 0, stream>>>(AO, Wot, (float*)d_out, 4096, 2048, 2048);
}